// Round 7
// baseline (1009.843 us; speedup 1.0000x reference)
//
#include <hip/hip_runtime.h>
#include <math.h>
#include <stdint.h>

#define N_TOK 16384
#define DDIM  384
#define KCODE 8192
#define EMA   0.99f
#define EPS_F 1e-5f
#define MARGIN 0.35f
#define NB 16            // KCODE / 512 code-blocks in coarse pass

typedef _Float16 f16x8 __attribute__((ext_vector_type(8)));
typedef float    f32x4 __attribute__((ext_vector_type(4)));

#define AS1(p) ((const __attribute__((address_space(1))) uint32_t*)(p))
#define AS3(p) ((__attribute__((address_space(3))) uint32_t*)(p))

// ---- ws byte offsets (max 12,779,784 B <= proven >=13,238,280 from R1) ----
// Region A [0, 12582912): phase1 = top3 partials + cb16; phase2 = embed accum
#define OFF_PD1    0UL         // rank r: pd at r*2097152, pi at r*2097152+1048576
#define OFF_CB16   6291456UL   // [KCODE*DDIM] f16 (6,291,456 B)
#define OFF_EMBED  0UL         // phase2: [KCODE*DDIM] f32 = 12,582,912 B
// persistent region (R6 BUGFIX: ws_idx/counts overlapped by 64 B -> wild
// codebook index -> page fault. counts moved to 12747008.)
#define OFF_CNORM  12582912UL  // [KCODE] f32 (32 KB)        -> ends 12615680
#define OFF_FLIST  12615680UL  // [N_TOK] i32 (64 KB)        -> ends 12681216
#define OFF_FCNT   12681216UL  // i32 + pad (256 B)          -> ends 12681472
#define OFF_WSIDX  12681472UL  // [N_TOK] i32 (64 KB)        -> ends 12747008
#define OFF_COUNTS 12747008UL  // [KCODE] f32 (32 KB)        -> ends 12779776
#define OFF_SUMSQ  12779776UL  // f32
#define OFF_NACC   12779780UL  // f32

__device__ __forceinline__ void insert3(float x, int xi, float d[3], int id[3]) {
    if (x < d[0] || (x == d[0] && xi < id[0])) {
        d[2] = d[1]; id[2] = id[1];
        d[1] = d[0]; id[1] = id[0];
        d[0] = x;    id[0] = xi;
    } else if (x < d[1]) {
        d[2] = d[1]; id[2] = id[1];
        d[1] = x;    id[1] = xi;
    } else if (x < d[2]) {
        d[2] = x;    id[2] = xi;
    }
}

// one wave per code: f16 copy of codebook + row sumsq
__global__ void cvtcb_kernel(const float* __restrict__ cb, _Float16* __restrict__ cb16,
                             float* __restrict__ cnorm) {
    int code = (blockIdx.x * blockDim.x + threadIdx.x) >> 6;
    int lane = threadIdx.x & 63;
    if (code >= KCODE) return;
    const float* row = cb + (size_t)code * DDIM;
    _Float16* row16 = cb16 + (size_t)code * DDIM;
    float s = 0.f;
    #pragma unroll
    for (int r = 0; r < 6; r++) {
        float v = row[lane + 64 * r];
        s += v * v;
        row16[lane + 64 * r] = (_Float16)v;
    }
    #pragma unroll
    for (int off = 32; off > 0; off >>= 1) s += __shfl_down(s, off, 64);
    if (lane == 0) cnorm[code] = s;
}

// ---- coarse pass: f16 MFMA, A direct global->reg, B via swizzled global_load_lds.
// 512 thr = 8 waves (wy x wx); wave 64 tok x 128 codes; block 128 x 512; BK=32.
// Emits per-token TOP-3 per 512-code block.
__launch_bounds__(512)
__global__ void argmin16_kernel(const float* __restrict__ z, const _Float16* __restrict__ cb16,
                                const float* __restrict__ cnorm, char* __restrict__ pbase) {
    __shared__ _Float16 Bs[512 * 32];   // 32 KB; epilogue arrays alias this after k-loop

    const int tid  = threadIdx.x;
    const int lane = tid & 63;
    const int wv   = tid >> 6;
    const int wy   = wv >> 2;
    const int wx   = wv & 3;
    const int m0   = blockIdx.x * 128;
    const int n0   = blockIdx.y * 512;
    const int l15  = lane & 15;
    const int l4   = lane >> 4;

    f32x4 acc[4][8];
    #pragma unroll
    for (int i = 0; i < 4; i++)
        #pragma unroll
        for (int j = 0; j < 8; j++) acc[i][j] = (f32x4){0.f, 0.f, 0.f, 0.f};

    // B DMA roles (proven R5): issue covers 16 rows; swizzle folded into global addr
    const int brow_i = lane >> 2;
    const int bclog  = (lane & 3) ^ ((lane >> 3) & 3);
    // fragment read swizzle
    const int fswz = (l4 ^ ((l15 >> 1) & 3)) * 8;

    // A global base: row per (im): m0 + wy*64 + im*16 + l15, cols kc + l4*8
    const float* abase = z + (size_t)(m0 + wy * 64 + l15) * DDIM + l4 * 8;

    // prefetch A for kc=0
    float4 a0[4], a1[4];
    #pragma unroll
    for (int im = 0; im < 4; im++) {
        const float* ap = abase + (size_t)im * 16 * DDIM;
        a0[im] = *(const float4*)(ap);
        a1[im] = *(const float4*)(ap + 4);
    }

    for (int kc = 0; kc < DDIM; kc += 32) {
        // stage B: async direct-to-LDS
        #pragma unroll
        for (int r = 0; r < 4; r++) {
            int issue = wv * 4 + r;
            int row   = issue * 16 + brow_i;
            const _Float16* gp = cb16 + (size_t)(n0 + row) * DDIM + kc + bclog * 8;
            __builtin_amdgcn_global_load_lds(AS1(gp), AS3(Bs + issue * 512), 16, 0, 0);
        }
        __syncthreads();   // drains B DMA and the in-flight A prefetch

        // convert prefetched A to f16 frags
        f16x8 af[4];
        #pragma unroll
        for (int im = 0; im < 4; im++) {
            f16x8 h;
            h[0]=(_Float16)a0[im].x; h[1]=(_Float16)a0[im].y; h[2]=(_Float16)a0[im].z; h[3]=(_Float16)a0[im].w;
            h[4]=(_Float16)a1[im].x; h[5]=(_Float16)a1[im].y; h[6]=(_Float16)a1[im].z; h[7]=(_Float16)a1[im].w;
            af[im] = h;
        }
        // prefetch A for next iter (completes during MFMA + next barrier)
        if (kc + 32 < DDIM) {
            #pragma unroll
            for (int im = 0; im < 4; im++) {
                const float* ap = abase + (size_t)im * 16 * DDIM + kc + 32;
                a0[im] = *(const float4*)(ap);
                a1[im] = *(const float4*)(ap + 4);
            }
        }

        f16x8 bf[8];
        #pragma unroll
        for (int in = 0; in < 8; in++)
            bf[in] = *(const f16x8*)(Bs + (wx * 128 + in * 16 + l15) * 32 + fswz);
        #pragma unroll
        for (int im = 0; im < 4; im++)
            #pragma unroll
            for (int in = 0; in < 8; in++)
                acc[im][in] = __builtin_amdgcn_mfma_f32_16x16x32_f16(af[im], bf[in], acc[im][in], 0, 0, 0);
        __syncthreads();
    }

    // epilogue arrays alias Bs (all B reads complete after final barrier)
    float* xd1 = (float*)Bs;           // [512]
    float* xd2 = xd1 + 512;
    float* xd3 = xd1 + 1024;
    int*   xi1 = (int*)(xd1 + 1536);
    int*   xi2 = (int*)(xd1 + 2048);
    int*   xi3 = (int*)(xd1 + 2560);

    // dist = ||c||^2 - 2 z.c ; C/D: col(code)=l15, row(token)=l4*4+reg [proven R4]
    float cn[8]; int cid[8];
    #pragma unroll
    for (int in = 0; in < 8; in++) {
        cid[in] = n0 + wx * 128 + in * 16 + l15;
        cn[in] = cnorm[cid[in]];
    }
    #pragma unroll
    for (int im = 0; im < 4; im++) {
        #pragma unroll
        for (int reg = 0; reg < 4; reg++) {
            float d[3] = {3.4e38f, 3.4e38f, 3.4e38f};
            int  id[3] = {0, 0, 0};
            #pragma unroll
            for (int in = 0; in < 8; in++)
                insert3(cn[in] - 2.f * acc[im][in][reg], cid[in], d, id);
            #pragma unroll
            for (int off = 1; off < 16; off <<= 1) {
                float od[3]; int oi[3];
                #pragma unroll
                for (int r = 0; r < 3; r++) {
                    od[r] = __shfl_xor(d[r], off, 16);
                    oi[r] = __shfl_xor(id[r], off, 16);
                }
                #pragma unroll
                for (int r = 0; r < 3; r++) insert3(od[r], oi[r], d, id);
            }
            if (l15 == 0) {
                int tl = wy * 64 + im * 16 + l4 * 4 + reg;
                xd1[tl * 4 + wx] = d[0]; xi1[tl * 4 + wx] = id[0];
                xd2[tl * 4 + wx] = d[1]; xi2[tl * 4 + wx] = id[1];
                xd3[tl * 4 + wx] = d[2]; xi3[tl * 4 + wx] = id[2];
            }
        }
    }
    __syncthreads();
    if (tid < 128) {
        float d[3] = {3.4e38f, 3.4e38f, 3.4e38f};
        int  id[3] = {0, 0, 0};
        #pragma unroll
        for (int x = 0; x < 4; x++) {
            insert3(xd1[tid * 4 + x], xi1[tid * 4 + x], d, id);
            insert3(xd2[tid * 4 + x], xi2[tid * 4 + x], d, id);
            insert3(xd3[tid * 4 + x], xi3[tid * 4 + x], d, id);
        }
        size_t o = (size_t)blockIdx.y * N_TOK + m0 + tid;
        #pragma unroll
        for (int r = 0; r < 3; r++) {
            *(float*)(pbase + (size_t)r * 2097152 + o * 4) = d[r];
            *(int*)  (pbase + (size_t)r * 2097152 + 1048576 + o * 4) = id[r];
        }
    }
}

// merge NB block-top entries -> global top-2; flag near-ties
__global__ void topmerge_kernel(const char* __restrict__ pbase,
                                int* __restrict__ ws_idx, float* __restrict__ out_idx,
                                int* __restrict__ fcnt, int* __restrict__ flist) {
    int t = blockIdx.x * blockDim.x + threadIdx.x;
    if (t >= N_TOK) return;
    const float* pd1 = (const float*)(pbase);
    const int*   pi1 = (const int*)(pbase + 1048576);
    const float* pd2 = (const float*)(pbase + 2097152);
    float d1 = 3.4e38f, d2 = 3.4e38f;
    int i1 = 0;
    for (int nb = 0; nb < NB; nb++) {
        size_t o = (size_t)nb * N_TOK + t;
        float od1 = pd1[o], od2 = pd2[o];
        int   oi1 = pi1[o];
        if (od1 < d1 || (od1 == d1 && oi1 < i1)) { d2 = fminf(d1, od2); d1 = od1; i1 = oi1; }
        else d2 = fminf(d2, od1);
    }
    ws_idx[t] = i1;
    out_idx[t] = (float)i1;
    if (d2 - d1 < MARGIN) {
        int s = atomicAdd(fcnt, 1);
        flist[s] = t;
    }
}

// exact fp32 rescore: one wave per flagged token, candidates = block-top3 within window
__launch_bounds__(256)
__global__ void rescore_kernel(const float* __restrict__ z, const float* __restrict__ cb,
                               const float* __restrict__ cnorm, const char* __restrict__ pbase,
                               const int* __restrict__ flist, const int* __restrict__ fcnt,
                               int* __restrict__ ws_idx, float* __restrict__ out_idx) {
    const int lane = threadIdx.x & 63;
    const int wv   = threadIdx.x >> 6;
    const int count = fcnt[0];
    const int nb = lane & 15, rk = lane >> 4;   // rk 0..3; rk==3 lanes inactive for scan

    for (int s = blockIdx.x * 4 + wv; s < count; s += gridDim.x * 4) {
        int tok = flist[s];
        // z fragment: lane holds z[tok*384 + lane + 64r], r=0..5 (coalesced)
        float zv[6];
        #pragma unroll
        for (int r = 0; r < 6; r++) zv[r] = z[(size_t)tok * DDIM + lane + 64 * r];
        // scan 48 candidate entries
        float ed = 3.4e38f; int ei = 0;
        if (rk < 3) {
            const char* b = pbase + (size_t)rk * 2097152;
            size_t o = (size_t)nb * N_TOK + tok;
            ed = ((const float*)b)[o];
            ei = ((const int*)(b + 1048576))[o];
        }
        // global coarse min across lanes
        float dmin = ed;
        #pragma unroll
        for (int off = 32; off > 0; off >>= 1) dmin = fminf(dmin, __shfl_xor(dmin, off, 64));
        unsigned long long mask = __ballot(ed < dmin + MARGIN);
        float bd = 3.4e38f; int bi = 0x7fffffff;
        while (mask) {
            int src = __ffsll((long long)mask) - 1;
            mask &= mask - 1;
            int c = __shfl(ei, src, 64);
            const float* cr = cb + (size_t)c * DDIM;
            float acc = 0.f;
            #pragma unroll
            for (int r = 0; r < 6; r++) acc = fmaf(zv[r], cr[lane + 64 * r], acc);
            #pragma unroll
            for (int off = 32; off > 0; off >>= 1) acc += __shfl_xor(acc, off, 64);
            float dist = cnorm[c] - 2.f * acc;
            if (dist < bd || (dist == bd && c < bi)) { bd = dist; bi = c; }
        }
        if (lane == 0) {
            ws_idx[tok] = bi;
            out_idx[tok] = (float)bi;
        }
    }
}

__global__ void gather_scatter_kernel(const float* __restrict__ z, const float* __restrict__ cb,
                                      const int* __restrict__ ws_idx,
                                      float* __restrict__ out_q, float* __restrict__ embed_ws,
                                      float* __restrict__ counts, float* __restrict__ sumsq) {
    int t = (blockIdx.x * blockDim.x + threadIdx.x) >> 6;
    int lane = threadIdx.x & 63;
    if (t >= N_TOK) return;
    int k = ws_idx[t];
    const float* zr = z + (size_t)t * DDIM;
    const float* cr = cb + (size_t)k * DDIM;
    float* qr = out_q + (size_t)t * DDIM;
    float* er = embed_ws + (size_t)k * DDIM;
    float s = 0.f;
    #pragma unroll
    for (int r = 0; r < 6; r++) {
        int d = lane + 64 * r;
        float zv = zr[d];
        float qv = cr[d];
        qr[d] = qv;
        float df = zv - qv;
        s += df * df;
        atomicAdd(er + d, zv);
    }
    #pragma unroll
    for (int off = 32; off > 0; off >>= 1) s += __shfl_down(s, off, 64);
    if (lane == 0) {
        atomicAdd(sumsq, s);
        atomicAdd(counts + k, 1.0f);
    }
}

__global__ void cluster_kernel(const float* __restrict__ ema_cs, const float* __restrict__ counts,
                               float* __restrict__ out_ncs, float* __restrict__ n_acc,
                               const float* __restrict__ sumsq, float* __restrict__ out_loss) {
    int i = blockIdx.x * blockDim.x + threadIdx.x;
    float v = 0.f;
    if (i < KCODE) {
        v = EMA * ema_cs[i] + (1.f - EMA) * counts[i];
        out_ncs[i] = v;
    }
    __shared__ float sm[4];
    int lane = threadIdx.x & 63, w = threadIdx.x >> 6;
    #pragma unroll
    for (int off = 32; off > 0; off >>= 1) v += __shfl_down(v, off, 64);
    if (lane == 0) sm[w] = v;
    __syncthreads();
    if (threadIdx.x == 0) {
        atomicAdd(n_acc, sm[0] + sm[1] + sm[2] + sm[3]);
        if (blockIdx.x == 0) {
            out_loss[0] = 1.25f * sumsq[0] / (float)(N_TOK * DDIM);
        }
    }
}

__global__ void codebook_kernel(const float* __restrict__ ema_es, const float* __restrict__ embed_ws,
                                const float* __restrict__ ncs, const float* __restrict__ n_acc,
                                float* __restrict__ out_es, float* __restrict__ out_cb) {
    int i = blockIdx.x * blockDim.x + threadIdx.x;
    if (i >= KCODE * DDIM) return;
    float es = EMA * ema_es[i] + (1.f - EMA) * embed_ws[i];
    out_es[i] = es;
    int k = i / DDIM;
    float n = n_acc[0];
    float smooth = (ncs[k] + EPS_F) / (n + (float)KCODE * EPS_F) * n;
    out_cb[i] = es / smooth;
}

extern "C" void kernel_launch(void* const* d_in, const int* in_sizes, int n_in,
                              void* d_out, int out_size, void* d_ws, size_t ws_size,
                              hipStream_t stream) {
    const float* z       = (const float*)d_in[0];
    const float* cb      = (const float*)d_in[1];
    const float* ema_cs  = (const float*)d_in[2];
    const float* ema_es  = (const float*)d_in[3];

    float* out      = (float*)d_out;
    float* out_q    = out;
    float* out_idx  = out + 6291456;
    float* out_loss = out + 6307840;
    float* out_ncs  = out + 6307841;
    float* out_es   = out + 6316033;
    float* out_cb   = out + 9461761;

    char* w = (char*)d_ws;
    char*      pbase  = w + OFF_PD1;
    _Float16*  cb16   = (_Float16*) (w + OFF_CB16);
    float*     cnorm  = (float*)    (w + OFF_CNORM);
    int*       flist  = (int*)      (w + OFF_FLIST);
    int*       fcnt   = (int*)      (w + OFF_FCNT);
    float*     embed  = (float*)    (w + OFF_EMBED);
    int*       ws_idx = (int*)      (w + OFF_WSIDX);
    float*     counts = (float*)    (w + OFF_COUNTS);
    float*     sumsq  = (float*)    (w + OFF_SUMSQ);
    float*     n_acc  = (float*)    (w + OFF_NACC);

    hipMemsetAsync(w + OFF_FCNT, 0, 256, stream);
    hipMemsetAsync(w + OFF_COUNTS, 0, 32768 + 8, stream);    // counts + sumsq + n_acc

    cvtcb_kernel<<<KCODE / 4, 256, 0, stream>>>(cb, cb16, cnorm);

    dim3 grid_am(N_TOK / 128, KCODE / 512, 1);
    argmin16_kernel<<<grid_am, 512, 0, stream>>>(z, cb16, cnorm, pbase);

    topmerge_kernel<<<N_TOK / 256, 256, 0, stream>>>(pbase, ws_idx, out_idx, fcnt, flist);

    rescore_kernel<<<256, 256, 0, stream>>>(z, cb, cnorm, pbase, flist, fcnt, ws_idx, out_idx);

    // phase1 scratch dead; reuse region A as embed-sum accumulator
    hipMemsetAsync(w + OFF_EMBED, 0, (size_t)KCODE * DDIM * sizeof(float), stream);

    gather_scatter_kernel<<<N_TOK * 64 / 256, 256, 0, stream>>>(z, cb, ws_idx, out_q, embed, counts, sumsq);
    cluster_kernel<<<(KCODE + 255) / 256, 256, 0, stream>>>(ema_cs, counts, out_ncs, n_acc, sumsq, out_loss);
    codebook_kernel<<<(KCODE * DDIM) / 256, 256, 0, stream>>>(ema_es, embed, out_ncs, n_acc, out_es, out_cb);
}

// Round 8
// 986.864 us; speedup vs baseline: 1.0233x; 1.0233x over previous
//
#include <hip/hip_runtime.h>
#include <math.h>
#include <stdint.h>

#define N_TOK 16384
#define DDIM  384
#define KCODE 8192
#define EMA   0.99f
#define EPS_F 1e-5f
#define MARGIN 0.35f
#define NB 16            // KCODE / 512 code-blocks in coarse pass

typedef _Float16 f16x8 __attribute__((ext_vector_type(8)));
typedef float    f32x4 __attribute__((ext_vector_type(4)));

#define AS1(p) ((const __attribute__((address_space(1))) uint32_t*)(p))
#define AS3(p) ((__attribute__((address_space(3))) uint32_t*)(p))

// ---- ws byte offsets (max 12,779,784 B; layout proven R7) ----
#define OFF_PD1    0UL         // rank r: pd at r*2097152, pi at r*2097152+1048576
#define OFF_CB16   6291456UL   // [KCODE*DDIM] f16 (6,291,456 B)
#define OFF_EMBED  0UL         // phase2: [KCODE*DDIM] f32 = 12,582,912 B
#define OFF_CNORM  12582912UL  // [KCODE] f32 (32 KB)        -> ends 12615680
#define OFF_FLIST  12615680UL  // [N_TOK] i32 (64 KB)        -> ends 12681216
#define OFF_FCNT   12681216UL  // i32 + pad (256 B)          -> ends 12681472
#define OFF_WSIDX  12681472UL  // [N_TOK] i32 (64 KB)        -> ends 12747008
#define OFF_COUNTS 12747008UL  // [KCODE] f32 (32 KB)        -> ends 12779776
#define OFF_SUMSQ  12779776UL  // f32
#define OFF_NACC   12779780UL  // f32

__device__ __forceinline__ void insert3(float x, int xi, float d[3], int id[3]) {
    if (x < d[0] || (x == d[0] && xi < id[0])) {
        d[2] = d[1]; id[2] = id[1];
        d[1] = d[0]; id[1] = id[0];
        d[0] = x;    id[0] = xi;
    } else if (x < d[1]) {
        d[2] = d[1]; id[2] = id[1];
        d[1] = x;    id[1] = xi;
    } else if (x < d[2]) {
        d[2] = x;    id[2] = xi;
    }
}

// one wave per code: f16 copy of codebook + row sumsq
__global__ void cvtcb_kernel(const float* __restrict__ cb, _Float16* __restrict__ cb16,
                             float* __restrict__ cnorm) {
    int code = (blockIdx.x * blockDim.x + threadIdx.x) >> 6;
    int lane = threadIdx.x & 63;
    if (code >= KCODE) return;
    const float* row = cb + (size_t)code * DDIM;
    _Float16* row16 = cb16 + (size_t)code * DDIM;
    float s = 0.f;
    #pragma unroll
    for (int r = 0; r < 6; r++) {
        float v = row[lane + 64 * r];
        s += v * v;
        row16[lane + 64 * r] = (_Float16)v;
    }
    #pragma unroll
    for (int off = 32; off > 0; off >>= 1) s += __shfl_down(s, off, 64);
    if (lane == 0) cnorm[code] = s;
}

// ---- coarse pass: f16 MFMA; B double-buffered via global_load_lds DMA,
// ONE barrier per k-iter (DMA for iter i+1 issued before iter i's barrier, so
// the mandatory vmcnt(0) drain lands after a full compute phase in flight).
// A direct global->reg, loaded one iter ahead. 8 waves; block 128x512; BK=32.
__launch_bounds__(512)
__global__ void argmin16_kernel(const float* __restrict__ z, const _Float16* __restrict__ cb16,
                                const float* __restrict__ cnorm, char* __restrict__ pbase) {
    __shared__ _Float16 Bs[2 * 512 * 32];   // 64 KB dbuf; epilogue aliases

    const int tid  = threadIdx.x;
    const int lane = tid & 63;
    const int wv   = tid >> 6;
    const int wy   = wv >> 2;
    const int wx   = wv & 3;
    const int m0   = blockIdx.x * 128;
    const int n0   = blockIdx.y * 512;
    const int l15  = lane & 15;
    const int l4   = lane >> 4;

    f32x4 acc[4][8];
    #pragma unroll
    for (int i = 0; i < 4; i++)
        #pragma unroll
        for (int j = 0; j < 8; j++) acc[i][j] = (f32x4){0.f, 0.f, 0.f, 0.f};

    // B DMA roles (proven R5): issue covers 16 rows; swizzle folded into global addr
    const int brow_i = lane >> 2;
    const int bclog  = (lane & 3) ^ ((lane >> 3) & 3);
    // fragment read swizzle
    const int fswz = (l4 ^ ((l15 >> 1) & 3)) * 8;

    // A global base: row per (im): m0 + wy*64 + im*16 + l15, cols kc + l4*8
    const float* abase = z + (size_t)(m0 + wy * 64 + l15) * DDIM + l4 * 8;

    // ---- prologue: B DMA for kc=0 into buf 0; A regs for kc=0 ----
    #pragma unroll
    for (int r = 0; r < 4; r++) {
        int issue = wv * 4 + r;
        int row   = issue * 16 + brow_i;
        const _Float16* gp = cb16 + (size_t)(n0 + row) * DDIM + bclog * 8;
        __builtin_amdgcn_global_load_lds(AS1(gp), AS3(Bs + issue * 512), 16, 0, 0);
    }
    float4 a0[4], a1[4];
    #pragma unroll
    for (int im = 0; im < 4; im++) {
        const float* ap = abase + (size_t)im * 16 * DDIM;
        a0[im] = *(const float4*)(ap);
        a1[im] = *(const float4*)(ap + 4);
    }
    __syncthreads();

    for (int kc = 0; kc < DDIM; kc += 32) {
        const int cur = (kc >> 5) & 1;
        const _Float16* bsc = Bs + cur * (512 * 32);

        // B frags from current buffer (ready per previous barrier)
        f16x8 bf[8];
        #pragma unroll
        for (int in = 0; in < 8; in++)
            bf[in] = *(const f16x8*)(bsc + (wx * 128 + in * 16 + l15) * 32 + fswz);

        // convert this iter's A (loaded last iter) to f16 frags
        f16x8 af[4];
        #pragma unroll
        for (int im = 0; im < 4; im++) {
            f16x8 h;
            h[0]=(_Float16)a0[im].x; h[1]=(_Float16)a0[im].y; h[2]=(_Float16)a0[im].z; h[3]=(_Float16)a0[im].w;
            h[4]=(_Float16)a1[im].x; h[5]=(_Float16)a1[im].y; h[6]=(_Float16)a1[im].z; h[7]=(_Float16)a1[im].w;
            af[im] = h;
        }

        // prefetch for next iter: B DMA into other buffer + A global->reg
        if (kc + 32 < DDIM) {
            _Float16* bsn = Bs + (cur ^ 1) * (512 * 32);
            #pragma unroll
            for (int r = 0; r < 4; r++) {
                int issue = wv * 4 + r;
                int row   = issue * 16 + brow_i;
                const _Float16* gp = cb16 + (size_t)(n0 + row) * DDIM + (kc + 32) + bclog * 8;
                __builtin_amdgcn_global_load_lds(AS1(gp), AS3(bsn + issue * 512), 16, 0, 0);
            }
            #pragma unroll
            for (int im = 0; im < 4; im++) {
                const float* ap = abase + (size_t)im * 16 * DDIM + kc + 32;
                a0[im] = *(const float4*)(ap);
                a1[im] = *(const float4*)(ap + 4);
            }
        }

        #pragma unroll
        for (int im = 0; im < 4; im++)
            #pragma unroll
            for (int in = 0; in < 8; in++)
                acc[im][in] = __builtin_amdgcn_mfma_f32_16x16x32_f16(af[im], bf[in], acc[im][in], 0, 0, 0);

        __syncthreads();   // releases cur for next DMA; drains in-flight prefetch
    }

    // epilogue arrays alias Bs (all B reads complete after final barrier)
    float* xd1 = (float*)Bs;           // [512]
    float* xd2 = xd1 + 512;
    float* xd3 = xd1 + 1024;
    int*   xi1 = (int*)(xd1 + 1536);
    int*   xi2 = (int*)(xd1 + 2048);
    int*   xi3 = (int*)(xd1 + 2560);

    // dist = ||c||^2 - 2 z.c ; C/D: col(code)=l15, row(token)=l4*4+reg [proven R4]
    float cn[8]; int cid[8];
    #pragma unroll
    for (int in = 0; in < 8; in++) {
        cid[in] = n0 + wx * 128 + in * 16 + l15;
        cn[in] = cnorm[cid[in]];
    }
    #pragma unroll
    for (int im = 0; im < 4; im++) {
        #pragma unroll
        for (int reg = 0; reg < 4; reg++) {
            float d[3] = {3.4e38f, 3.4e38f, 3.4e38f};
            int  id[3] = {0, 0, 0};
            #pragma unroll
            for (int in = 0; in < 8; in++)
                insert3(cn[in] - 2.f * acc[im][in][reg], cid[in], d, id);
            #pragma unroll
            for (int off = 1; off < 16; off <<= 1) {
                float od[3]; int oi[3];
                #pragma unroll
                for (int r = 0; r < 3; r++) {
                    od[r] = __shfl_xor(d[r], off, 16);
                    oi[r] = __shfl_xor(id[r], off, 16);
                }
                #pragma unroll
                for (int r = 0; r < 3; r++) insert3(od[r], oi[r], d, id);
            }
            if (l15 == 0) {
                int tl = wy * 64 + im * 16 + l4 * 4 + reg;
                xd1[tl * 4 + wx] = d[0]; xi1[tl * 4 + wx] = id[0];
                xd2[tl * 4 + wx] = d[1]; xi2[tl * 4 + wx] = id[1];
                xd3[tl * 4 + wx] = d[2]; xi3[tl * 4 + wx] = id[2];
            }
        }
    }
    __syncthreads();
    if (tid < 128) {
        float d[3] = {3.4e38f, 3.4e38f, 3.4e38f};
        int  id[3] = {0, 0, 0};
        #pragma unroll
        for (int x = 0; x < 4; x++) {
            insert3(xd1[tid * 4 + x], xi1[tid * 4 + x], d, id);
            insert3(xd2[tid * 4 + x], xi2[tid * 4 + x], d, id);
            insert3(xd3[tid * 4 + x], xi3[tid * 4 + x], d, id);
        }
        size_t o = (size_t)blockIdx.y * N_TOK + m0 + tid;
        #pragma unroll
        for (int r = 0; r < 3; r++) {
            *(float*)(pbase + (size_t)r * 2097152 + o * 4) = d[r];
            *(int*)  (pbase + (size_t)r * 2097152 + 1048576 + o * 4) = id[r];
        }
    }
}

// merge NB block-top entries -> global top-2; flag near-ties
__global__ void topmerge_kernel(const char* __restrict__ pbase,
                                int* __restrict__ ws_idx, float* __restrict__ out_idx,
                                int* __restrict__ fcnt, int* __restrict__ flist) {
    int t = blockIdx.x * blockDim.x + threadIdx.x;
    if (t >= N_TOK) return;
    const float* pd1 = (const float*)(pbase);
    const int*   pi1 = (const int*)(pbase + 1048576);
    const float* pd2 = (const float*)(pbase + 2097152);
    float d1 = 3.4e38f, d2 = 3.4e38f;
    int i1 = 0;
    for (int nb = 0; nb < NB; nb++) {
        size_t o = (size_t)nb * N_TOK + t;
        float od1 = pd1[o], od2 = pd2[o];
        int   oi1 = pi1[o];
        if (od1 < d1 || (od1 == d1 && oi1 < i1)) { d2 = fminf(d1, od2); d1 = od1; i1 = oi1; }
        else d2 = fminf(d2, od1);
    }
    ws_idx[t] = i1;
    out_idx[t] = (float)i1;
    if (d2 - d1 < MARGIN) {
        int s = atomicAdd(fcnt, 1);
        flist[s] = t;
    }
}

// exact fp32 rescore: one wave per flagged token, candidates = block-top3 within window
__launch_bounds__(256)
__global__ void rescore_kernel(const float* __restrict__ z, const float* __restrict__ cb,
                               const float* __restrict__ cnorm, const char* __restrict__ pbase,
                               const int* __restrict__ flist, const int* __restrict__ fcnt,
                               int* __restrict__ ws_idx, float* __restrict__ out_idx) {
    const int lane = threadIdx.x & 63;
    const int wv   = threadIdx.x >> 6;
    const int count = fcnt[0];
    const int nb = lane & 15, rk = lane >> 4;   // rk 0..3; rk==3 lanes inactive for scan

    for (int s = blockIdx.x * 4 + wv; s < count; s += gridDim.x * 4) {
        int tok = flist[s];
        float zv[6];
        #pragma unroll
        for (int r = 0; r < 6; r++) zv[r] = z[(size_t)tok * DDIM + lane + 64 * r];
        float ed = 3.4e38f; int ei = 0;
        if (rk < 3) {
            const char* b = pbase + (size_t)rk * 2097152;
            size_t o = (size_t)nb * N_TOK + tok;
            ed = ((const float*)b)[o];
            ei = ((const int*)(b + 1048576))[o];
        }
        float dmin = ed;
        #pragma unroll
        for (int off = 32; off > 0; off >>= 1) dmin = fminf(dmin, __shfl_xor(dmin, off, 64));
        unsigned long long mask = __ballot(ed < dmin + MARGIN);
        float bd = 3.4e38f; int bi = 0x7fffffff;
        while (mask) {
            int src = __ffsll((long long)mask) - 1;
            mask &= mask - 1;
            int c = __shfl(ei, src, 64);
            const float* cr = cb + (size_t)c * DDIM;
            float acc = 0.f;
            #pragma unroll
            for (int r = 0; r < 6; r++) acc = fmaf(zv[r], cr[lane + 64 * r], acc);
            #pragma unroll
            for (int off = 32; off > 0; off >>= 1) acc += __shfl_xor(acc, off, 64);
            float dist = cnorm[c] - 2.f * acc;
            if (dist < bd || (dist == bd && c < bi)) { bd = dist; bi = c; }
        }
        if (lane == 0) {
            ws_idx[tok] = bi;
            out_idx[tok] = (float)bi;
        }
    }
}

__global__ void gather_scatter_kernel(const float* __restrict__ z, const float* __restrict__ cb,
                                      const int* __restrict__ ws_idx,
                                      float* __restrict__ out_q, float* __restrict__ embed_ws,
                                      float* __restrict__ counts, float* __restrict__ sumsq) {
    int t = (blockIdx.x * blockDim.x + threadIdx.x) >> 6;
    int lane = threadIdx.x & 63;
    if (t >= N_TOK) return;
    int k = ws_idx[t];
    const float* zr = z + (size_t)t * DDIM;
    const float* cr = cb + (size_t)k * DDIM;
    float* qr = out_q + (size_t)t * DDIM;
    float* er = embed_ws + (size_t)k * DDIM;
    float s = 0.f;
    #pragma unroll
    for (int r = 0; r < 6; r++) {
        int d = lane + 64 * r;
        float zv = zr[d];
        float qv = cr[d];
        qr[d] = qv;
        float df = zv - qv;
        s += df * df;
        atomicAdd(er + d, zv);
    }
    #pragma unroll
    for (int off = 32; off > 0; off >>= 1) s += __shfl_down(s, off, 64);
    if (lane == 0) {
        atomicAdd(sumsq, s);
        atomicAdd(counts + k, 1.0f);
    }
}

__global__ void cluster_kernel(const float* __restrict__ ema_cs, const float* __restrict__ counts,
                               float* __restrict__ out_ncs, float* __restrict__ n_acc,
                               const float* __restrict__ sumsq, float* __restrict__ out_loss) {
    int i = blockIdx.x * blockDim.x + threadIdx.x;
    float v = 0.f;
    if (i < KCODE) {
        v = EMA * ema_cs[i] + (1.f - EMA) * counts[i];
        out_ncs[i] = v;
    }
    __shared__ float sm[4];
    int lane = threadIdx.x & 63, w = threadIdx.x >> 6;
    #pragma unroll
    for (int off = 32; off > 0; off >>= 1) v += __shfl_down(v, off, 64);
    if (lane == 0) sm[w] = v;
    __syncthreads();
    if (threadIdx.x == 0) {
        atomicAdd(n_acc, sm[0] + sm[1] + sm[2] + sm[3]);
        if (blockIdx.x == 0) {
            out_loss[0] = 1.25f * sumsq[0] / (float)(N_TOK * DDIM);
        }
    }
}

__global__ void codebook_kernel(const float* __restrict__ ema_es, const float* __restrict__ embed_ws,
                                const float* __restrict__ ncs, const float* __restrict__ n_acc,
                                float* __restrict__ out_es, float* __restrict__ out_cb) {
    int i = blockIdx.x * blockDim.x + threadIdx.x;
    if (i >= KCODE * DDIM) return;
    float es = EMA * ema_es[i] + (1.f - EMA) * embed_ws[i];
    out_es[i] = es;
    int k = i / DDIM;
    float n = n_acc[0];
    float smooth = (ncs[k] + EPS_F) / (n + (float)KCODE * EPS_F) * n;
    out_cb[i] = es / smooth;
}

extern "C" void kernel_launch(void* const* d_in, const int* in_sizes, int n_in,
                              void* d_out, int out_size, void* d_ws, size_t ws_size,
                              hipStream_t stream) {
    const float* z       = (const float*)d_in[0];
    const float* cb      = (const float*)d_in[1];
    const float* ema_cs  = (const float*)d_in[2];
    const float* ema_es  = (const float*)d_in[3];

    float* out      = (float*)d_out;
    float* out_q    = out;
    float* out_idx  = out + 6291456;
    float* out_loss = out + 6307840;
    float* out_ncs  = out + 6307841;
    float* out_es   = out + 6316033;
    float* out_cb   = out + 9461761;

    char* w = (char*)d_ws;
    char*      pbase  = w + OFF_PD1;
    _Float16*  cb16   = (_Float16*) (w + OFF_CB16);
    float*     cnorm  = (float*)    (w + OFF_CNORM);
    int*       flist  = (int*)      (w + OFF_FLIST);
    int*       fcnt   = (int*)      (w + OFF_FCNT);
    float*     embed  = (float*)    (w + OFF_EMBED);
    int*       ws_idx = (int*)      (w + OFF_WSIDX);
    float*     counts = (float*)    (w + OFF_COUNTS);
    float*     sumsq  = (float*)    (w + OFF_SUMSQ);
    float*     n_acc  = (float*)    (w + OFF_NACC);

    hipMemsetAsync(w + OFF_FCNT, 0, 256, stream);
    hipMemsetAsync(w + OFF_COUNTS, 0, 32768 + 8, stream);    // counts + sumsq + n_acc

    cvtcb_kernel<<<KCODE / 4, 256, 0, stream>>>(cb, cb16, cnorm);

    dim3 grid_am(N_TOK / 128, KCODE / 512, 1);
    argmin16_kernel<<<grid_am, 512, 0, stream>>>(z, cb16, cnorm, pbase);

    topmerge_kernel<<<N_TOK / 256, 256, 0, stream>>>(pbase, ws_idx, out_idx, fcnt, flist);

    rescore_kernel<<<256, 256, 0, stream>>>(z, cb, cnorm, pbase, flist, fcnt, ws_idx, out_idx);

    // phase1 scratch dead; reuse region A as embed-sum accumulator
    hipMemsetAsync(w + OFF_EMBED, 0, (size_t)KCODE * DDIM * sizeof(float), stream);

    gather_scatter_kernel<<<N_TOK * 64 / 256, 256, 0, stream>>>(z, cb, ws_idx, out_q, embed, counts, sumsq);
    cluster_kernel<<<(KCODE + 255) / 256, 256, 0, stream>>>(ema_cs, counts, out_ncs, n_acc, sumsq, out_loss);
    codebook_kernel<<<(KCODE * DDIM) / 256, 256, 0, stream>>>(ema_es, embed, out_ncs, n_acc, out_es, out_cb);
}